// Round 7
// baseline (108.379 us; speedup 1.0000x reference)
//
#include <hip/hip_runtime.h>
#include <stdint.h>

// Problem constants (match reference)
#define Bn   256
#define Dn   2048
#define Sn   8
#define ON   1000

// Tiling
#define ROWS 64             // max samples per subject (binomial mean 32; 6+ sigma)
#define OT   256            // o per block (4 oc blocks; oc=3 ragged, clamped)
#define KS   256            // k per block
#define NDC  (Dn / KS)      // 8 part slices
#define STK  32             // k per sub-tile
#define NST  (KS / STK)     // 8 sub-tiles
#define NBUF 7              // private LDS buffers (st7 reuses buf0 after MFMA st0)
#define LDKS 40             // shorts per o-row: 32 k + 8 pad = 80B (16B multiple)
#define SUBB (OT * LDKS * 2) // bytes per sub-tile buffer = 20480

typedef short v8s __attribute__((ext_vector_type(8)));
typedef short v4s __attribute__((ext_vector_type(4)));
typedef float v4f __attribute__((ext_vector_type(4)));

// fp32 -> bf16 round-to-nearest-even
static __device__ __forceinline__ short f2bf(float f) {
    union { float f; uint32_t u; } v; v.f = f;
    uint32_t u = v.u;
    u += 0x7FFFu + ((u >> 16) & 1u);
    return (short)(u >> 16);
}

// Main kernel: grid (4 oc, 8 kc, 8 s) = 256 blocks, 512 threads (8 waves).
// R5/R6-proven core: 1KB-contiguous W wave-loads along o; register 4o x 4k
// transpose -> granule-XOR-swizzled [o][k] bf16 LDS; depth-3 W ring; A
// inline from x (loads issued first).
// NEW vs R6: BARRIER-FREE STAGING. 7 private sub-tile buffers (143.4 KiB of
// the 160 KiB LDS) let all 8 waves pipeline their staging streams with NO
// per-sub-tile lockstep (the m233-measured 2-phase stall). Only 3 barriers:
// {all staged 0-6} -> MFMA st0 -> {buf0 free} -> write st7 -> {st7 ready}
// -> MFMA st1..7 uninterrupted.
__global__ __launch_bounds__(512) void main_kernel(const float* __restrict__ x,
                                                   const int* __restrict__ sid,
                                                   const float* __restrict__ W,
                                                   float* __restrict__ part) {
    __shared__ unsigned short Bsh[NBUF][OT * LDKS];   // 7 x 20480 B = 143,360 B
    __shared__ unsigned long long bmask[8];
    __shared__ int rows_l[ROWS];

    const int oc = blockIdx.x;   // 0..3
    const int kc = blockIdx.y;   // 0..7
    const int s  = blockIdx.z;   // 0..7
    const int o0 = oc * OT;
    const int k0 = kc * KS;
    const int t  = threadIdx.x;
    const int lane = t & 63;
    const int w    = t >> 6;     // 0..7

    // ---- bucket samples of subject s via ballot (prefix-dense rows_l) ----
    const int mysid = (t < Bn) ? sid[t] : -1;
    const bool match = (mysid == s);
    const unsigned long long m = __ballot(match);
    if (lane == 0) bmask[w] = m;
    if (t < ROWS) rows_l[t] = -1;
    __syncthreads();
    if (match) {
        int pos = __popcll(m & ((1ull << lane) - 1ull));
        for (int ww = 0; ww < w; ++ww) pos += __popcll(bmask[ww]);
        if (pos < ROWS) rows_l[pos] = t;
    }
    __syncthreads();

    // ---- W staging geometry: wave w covers k-rows 4w..4w+3 of each sub-tile;
    //      lane covers o = o0 + 4*lane .. +3 (contiguous 1KB per wave-instr) ----
    int og = o0 + 4 * lane;
    if (og > ON - 4) og = ON - 4;               // oc=3 ragged: duplicate loads, local col kept
    const float* wpb = W + ((size_t)s * Dn + k0 + 4 * w) * ON + og;

    // LDS write addrs (buffer 0): b64 of k=4w..4w+3 at o=4*lane+i.
    // byte = o*80 + 16*((w>>1) ^ (lane&3)) + 8*(w&1)   [granule-XOR swizzle]
    unsigned short* wr[4];
#pragma unroll
    for (int i = 0; i < 4; ++i)
        wr[i] = (unsigned short*)((char*)&Bsh[0][0]
                + (4 * lane + i) * 80 + 16 * ((w >> 1) ^ (lane & 3)) + 8 * (w & 1));

    // ---- A geometry: wave w -> rows (w>>1)*16..+15, o-half (w&1) ----
    const int lo16 = lane & 15;
    const int quad = lane >> 4;
    const int arow = (w >> 1) * 16 + lo16;
    const int xrow = rows_l[arow];
    const bool wactive = (rows_l[(w >> 1) * 16] >= 0);    // prefix-dense
    const float* xp = (xrow >= 0 ? x + (size_t)xrow * Dn : x) + k0 + quad * 8;

    // ---- A loads issued FIRST (L2/L3-resident x, oldest in vmcnt order so
    //      waiting on them never drains the younger W stream) ----
    float4 a0[NST], a1[NST];
#pragma unroll
    for (int st = 0; st < NST; ++st) {
        a0[st] = *(const float4*)(xp + st * STK);
        a1[st] = *(const float4*)(xp + st * STK + 4);
    }

    // ---- W prologue: issue sub-tiles 0,1,2 (depth-3 ring) ----
    v4f fb[3][4];
#pragma unroll
    for (int c = 0; c < 3; ++c)
#pragma unroll
        for (int r = 0; r < 4; ++r)
            fb[c][r] = *(const v4f*)(wpb + ((size_t)c * STK + r) * ON);

    // ---- convert A to bf16 fragments (frees the 64 raw VGPRs) ----
    v8s af[NST];
#pragma unroll
    for (int st = 0; st < NST; ++st) {
        v8s a;
        a[0] = f2bf(a0[st].x); a[1] = f2bf(a0[st].y);
        a[2] = f2bf(a0[st].z); a[3] = f2bf(a0[st].w);
        a[4] = f2bf(a1[st].x); a[5] = f2bf(a1[st].y);
        a[6] = f2bf(a1[st].z); a[7] = f2bf(a1[st].w);
        af[st] = a;
    }

    // B-frag read base: o_loc = (w&1)*128 + nt*16 + lo16; granule swizzle by lo16
    const int rb0  = (w & 1) * 128 + lo16;
    const int rswz = 16 * (quad ^ ((lo16 >> 2) & 3));

    v4f acc[8];
#pragma unroll
    for (int i = 0; i < 8; ++i) acc[i] = (v4f){0.f, 0.f, 0.f, 0.f};

    // ---- stage sub-tiles 0..6 into private buffers: NO barriers, each wave
    //      free-runs its own load->cvt->write pipeline (8-wave desync/CU) ----
#pragma unroll
    for (int st = 0; st < NBUF; ++st) {
        const int rg = st % 3;
#pragma unroll
        for (int i = 0; i < 4; ++i) {
            v4s kv;
            kv[0] = f2bf(fb[rg][0][i]);
            kv[1] = f2bf(fb[rg][1][i]);
            kv[2] = f2bf(fb[rg][2][i]);
            kv[3] = f2bf(fb[rg][3][i]);
            *(v4s*)((char*)wr[i] + st * SUBB) = kv;
        }
        if (st + 3 < NST) {     // st=4 issues st7 into fb[1]; it stays live
#pragma unroll
            for (int r = 0; r < 4; ++r)
                fb[rg][r] = *(const v4f*)(wpb + ((size_t)(st + 3) * STK + r) * ON);
        }
    }
    asm volatile("s_waitcnt lgkmcnt(0)" ::: "memory");
    __builtin_amdgcn_s_barrier();           // buffers 0..6 ready
    asm volatile("" ::: "memory");

    // ---- MFMA sub-tile 0 (frees buffer 0) ----
    if (wactive) {
        const v8s a = af[0];
        const char* bb = (const char*)&Bsh[0][0];
#pragma unroll
        for (int nt = 0; nt < 8; ++nt) {
            const v8s bf = *(const v8s*)(bb + (rb0 + nt * 16) * 80 + rswz);
            acc[nt] = __builtin_amdgcn_mfma_f32_16x16x32_bf16(a, bf, acc[nt], 0, 0, 0);
        }
    }
    __builtin_amdgcn_s_barrier();           // all waves done reading buffer 0
    asm volatile("" ::: "memory");

    // ---- stage sub-tile 7 into buffer 0 (data held in fb[1] since st=4) ----
#pragma unroll
    for (int i = 0; i < 4; ++i) {
        v4s kv;
        kv[0] = f2bf(fb[1][0][i]);
        kv[1] = f2bf(fb[1][1][i]);
        kv[2] = f2bf(fb[1][2][i]);
        kv[3] = f2bf(fb[1][3][i]);
        *(v4s*)((char*)wr[i]) = kv;
    }
    asm volatile("s_waitcnt lgkmcnt(0)" ::: "memory");
    __builtin_amdgcn_s_barrier();           // sub-tile 7 ready
    asm volatile("" ::: "memory");

    // ---- MFMA sub-tiles 1..7, uninterrupted ----
    if (wactive) {
#pragma unroll
        for (int st = 1; st < NST; ++st) {
            const v8s a = af[st];
            const char* bb = (const char*)&Bsh[(st < NBUF) ? st : 0][0];
#pragma unroll
            for (int nt = 0; nt < 8; ++nt) {
                const v8s bf = *(const v8s*)(bb + (rb0 + nt * 16) * 80 + rswz);
                acc[nt] = __builtin_amdgcn_mfma_f32_16x16x32_bf16(a, bf, acc[nt],
                                                                  0, 0, 0);
            }
        }
    }

    // ---- epilogue: C/D layout col=lane&15, row=quad*4+reg ----
    if (wactive) {
        float* pp = part + (size_t)kc * Bn * ON;
        const int er0 = (w >> 1) * 16 + quad * 4;
#pragma unroll
        for (int nt = 0; nt < 8; ++nt) {
            const int o = o0 + (w & 1) * 128 + nt * 16 + lo16;
            if (o < ON) {
#pragma unroll
                for (int r = 0; r < 4; ++r) {
                    const int bi = rows_l[er0 + r];
                    if (bi >= 0) pp[(size_t)bi * ON + o] = acc[nt][r];
                }
            }
        }
    }
}

// Reduce: out[b][o] = bias[sid[b]][o] + sum_kc part[kc][b][o]  (float4 lanes)
__global__ __launch_bounds__(256) void reduce_kernel(const int* __restrict__ sid,
                                                     const float* __restrict__ bias,
                                                     const float* __restrict__ part,
                                                     float* __restrict__ out) {
    const int b = blockIdx.x;
    const int s = sid[b];
    const int o = threadIdx.x * 4;
    if (o < ON) {          // ON=1000 -> 250 active float4 lanes
        float4 v = *(const float4*)(bias + (size_t)s * ON + o);
#pragma unroll
        for (int d = 0; d < NDC; d++) {
            const float4 p = *(const float4*)(part + ((size_t)d * Bn + b) * ON + o);
            v.x += p.x; v.y += p.y; v.z += p.z; v.w += p.w;
        }
        *(float4*)(out + (size_t)b * ON + o) = v;
    }
}

extern "C" void kernel_launch(void* const* d_in, const int* in_sizes, int n_in,
                              void* d_out, int out_size, void* d_ws, size_t ws_size,
                              hipStream_t stream) {
    const float* x    = (const float*)d_in[0];
    const int*   sid  = (const int*)d_in[1];
    const float* W    = (const float*)d_in[2];
    const float* bias = (const float*)d_in[3];
    float*       out  = (float*)d_out;
    float*       part = (float*)d_ws;   // NDC*Bn*ON floats = 8.192 MB

    main_kernel<<<dim3(4, NDC, Sn), dim3(512), 0, stream>>>(x, sid, W, part);
    reduce_kernel<<<dim3(Bn), dim3(256), 0, stream>>>(sid, bias, part, out);
}